// Round 16
// baseline (79.149 us; speedup 1.0000x reference)
//
#include <hip/hip_runtime.h>
#include <hip/hip_bf16.h>

typedef __attribute__((ext_vector_type(4))) float f32x4;
typedef __attribute__((ext_vector_type(8))) short short8;
typedef __attribute__((ext_vector_type(8))) unsigned short ushort8;
typedef __attribute__((ext_vector_type(4))) unsigned short ushort4v;

#define M_ROWS 16384
#define KDIM 512
#define UDIM 512
#define IN_STRIDE 1024

__device__ __forceinline__ unsigned short f2bf(float f) {
    union { float f; unsigned u; } v; v.f = f;
    unsigned r = v.u + 0x7FFFu + ((v.u >> 16) & 1u);  // RTNE
    return (unsigned short)(r >> 16);
}

// packed RNE f32x2 -> bf16x2 (compiler emits v_cvt_pk_bf16_f32)
__device__ __forceinline__ unsigned cvt2(float a, float b) {
    __hip_bfloat162 h = __float22bfloat162_rn(float2{a, b});
    union { __hip_bfloat162 h; unsigned u; } c; c.h = h; return c.u;
}

// global_load_lds, width 16 (literal required)
#define GLD16(g, l)                                                            \
    __builtin_amdgcn_global_load_lds(                                          \
        (const __attribute__((address_space(1))) void*)(g),                    \
        (__attribute__((address_space(3))) void*)(l), 16, 0, 0)

// ---------------------------------------------------------------------------
// weights pack: Wp[bx 16][chunk 2][slot 2048] x 16B.
// slot s: jj = s>>5 (0..63: <32 -> w_z col, else w_h), piece p = s&31,
// content k-octet q = p ^ (jj&7)  (LDS piece-XOR swizzle baked), i.e. holds
// w[c*256 + q*8 .. +8][bx*32 + (jj&31)] as bf16x8. Linear for global_load_lds.
// ---------------------------------------------------------------------------
__global__ __launch_bounds__(256) void pack_w(
    const float* __restrict__ w_z,
    const float* __restrict__ w_h,
    unsigned short* __restrict__ Wp)
{
    int g  = blockIdx.x * 256 + threadIdx.x;   // [0, 65536)
    int s  = g & 2047;
    int c  = (g >> 11) & 1;
    int bx = g >> 12;
    int jj = s >> 5;
    int p  = s & 31;
    int q  = p ^ (jj & 7);
    int k0 = c * 256 + q * 8;
    const float* w = (jj >= 32) ? w_h : w_z;
    int u = bx * 32 + (jj & 31);
    ushort8 v;
#pragma unroll
    for (int i = 0; i < 8; ++i)
        v[i] = f2bf(w[(size_t)(k0 + i) * UDIM + u]);
    *reinterpret_cast<ushort8*>(Wp + (size_t)g * 8) = v;
}

// ---------------------------------------------------------------------------
// Free-run GEMM: 128(M) x 64(jj) tile, 4 waves (wave = 32 rows x 64 jj),
// NO barriers in the K-loop.
//  B: read-only 32KB LDS tile [64 jj][256 k] bf16 (piece-XOR swizzled),
//     staged once per 256-k chunk via global_load_lds (2 chunks total).
//  A: x fp32 read per-wave direct from global into a depth-3 register ring
//     (no LDS, no cross-wave sharing), v_cvt_pk_bf16_f32 at consume time.
//  Compiler-managed per-use vmcnt/lgkmcnt; only 3 __syncthreads total.
//  32KB LDS -> 4 blocks/CU; VGPR target <=128 -> 16 waves/CU.
// ---------------------------------------------------------------------------
__global__ __launch_bounds__(256, 4) void gru_gemm(
    const float* __restrict__ x,            // (16384, 1024), cols [0,512) used
    const unsigned short* __restrict__ Wp,  // packed weights (1 MiB)
    const float* __restrict__ b_z,
    const float* __restrict__ b_h,
    float* __restrict__ out)
{
    __shared__ __align__(16) unsigned short shB[16384];   // 32 KB: one chunk

    const int tid  = threadIdx.x;
    const int lane = tid & 63;
    const int wid  = tid >> 6;

    // XCD swizzle: the 16 jj-tiles sharing a row-panel land on one XCD
    const int d   = blockIdx.x;              // [0,2048)
    const int c8  = d & 7;
    const int idx = d >> 3;
    const int bx  = idx & 15;                // jj-tile
    const int by  = c8 * 16 + (idx >> 4);    // row-panel (bijective)
    const int u0   = bx * 32;
    const int brow = by * 128;

    const int fr  = lane & 15;
    const int ks  = lane >> 4;
    const int fx7 = fr & 7;

    // A fragment pointers: wave rows wid*32 .. +31, two 16-row frags
    const float* gA0 = x + (size_t)(brow + wid * 32 + fr) * IN_STRIDE + ks * 8;
    const float* gA1 = gA0 + 16 * IN_STRIDE;

    // B stage source (chunk stride 2048 slots * 8 u16)
    const unsigned short* bp = Wp + (size_t)bx * 32768;

    // B fragment row bases (u16 units)
    const int bof0 = (0 * 16 + fr) * 256;
    const int bof1 = (1 * 16 + fr) * 256;
    const int bof2 = (2 * 16 + fr) * 256;
    const int bof3 = (3 * 16 + fr) * 256;

    f32x4 acc[2][4];
#pragma unroll
    for (int m = 0; m < 2; ++m)
#pragma unroll
        for (int n = 0; n < 4; ++n)
            acc[m][n] = (f32x4){0.f, 0.f, 0.f, 0.f};

    f32x4 rA[3][4];   // depth-3 A ring; indices static under full unroll

#define ISSUE_A(g, s)                                                          \
    {                                                                          \
        rA[s][0] = *reinterpret_cast<const f32x4*>(gA0 + (g) * 32);            \
        rA[s][1] = *reinterpret_cast<const f32x4*>(gA0 + (g) * 32 + 4);        \
        rA[s][2] = *reinterpret_cast<const f32x4*>(gA1 + (g) * 32);            \
        rA[s][3] = *reinterpret_cast<const f32x4*>(gA1 + (g) * 32 + 4);        \
    }

#define STAGE_B(c)                                                             \
    {                                                                          \
        _Pragma("unroll")                                                      \
        for (int i = 0; i < 8; ++i)                                            \
            GLD16(bp + (size_t)(c) * 16384 + (i * 256 + wid * 64 + lane) * 8,  \
                  shB + (i * 256 + wid * 64) * 8);                             \
    }

#define BODY(g, tl, s)                                                         \
    {                                                                          \
        short8 af0, af1;                                                       \
        {                                                                      \
            union { unsigned u[4]; short8 v; } ca, cb;                         \
            ca.u[0] = cvt2(rA[s][0][0], rA[s][0][1]);                          \
            ca.u[1] = cvt2(rA[s][0][2], rA[s][0][3]);                          \
            ca.u[2] = cvt2(rA[s][1][0], rA[s][1][1]);                          \
            ca.u[3] = cvt2(rA[s][1][2], rA[s][1][3]);                          \
            cb.u[0] = cvt2(rA[s][2][0], rA[s][2][1]);                          \
            cb.u[1] = cvt2(rA[s][2][2], rA[s][2][3]);                          \
            cb.u[2] = cvt2(rA[s][3][0], rA[s][3][1]);                          \
            cb.u[3] = cvt2(rA[s][3][2], rA[s][3][3]);                          \
            af0 = ca.v; af1 = cb.v;                                            \
        }                                                                      \
        if ((g) + 3 < 16) ISSUE_A((g) + 3, s);                                 \
        const int po = (((tl) * 4 + ks) ^ fx7) * 8;                            \
        short8 bf0 = *reinterpret_cast<const short8*>(&shB[bof0 + po]);        \
        short8 bf1 = *reinterpret_cast<const short8*>(&shB[bof1 + po]);        \
        short8 bf2 = *reinterpret_cast<const short8*>(&shB[bof2 + po]);        \
        short8 bf3 = *reinterpret_cast<const short8*>(&shB[bof3 + po]);        \
        acc[0][0] = __builtin_amdgcn_mfma_f32_16x16x32_bf16(af0, bf0, acc[0][0], 0, 0, 0); \
        acc[0][1] = __builtin_amdgcn_mfma_f32_16x16x32_bf16(af0, bf1, acc[0][1], 0, 0, 0); \
        acc[0][2] = __builtin_amdgcn_mfma_f32_16x16x32_bf16(af0, bf2, acc[0][2], 0, 0, 0); \
        acc[0][3] = __builtin_amdgcn_mfma_f32_16x16x32_bf16(af0, bf3, acc[0][3], 0, 0, 0); \
        acc[1][0] = __builtin_amdgcn_mfma_f32_16x16x32_bf16(af1, bf0, acc[1][0], 0, 0, 0); \
        acc[1][1] = __builtin_amdgcn_mfma_f32_16x16x32_bf16(af1, bf1, acc[1][1], 0, 0, 0); \
        acc[1][2] = __builtin_amdgcn_mfma_f32_16x16x32_bf16(af1, bf2, acc[1][2], 0, 0, 0); \
        acc[1][3] = __builtin_amdgcn_mfma_f32_16x16x32_bf16(af1, bf3, acc[1][3], 0, 0, 0); \
    }

    // prologue: A sets 0..2 + B chunk 0 in flight; one full sync
    ISSUE_A(0, 0);
    ISSUE_A(1, 1);
    ISSUE_A(2, 2);
    STAGE_B(0);
    __syncthreads();   // drains vmcnt (B0 + A0..2 landed), all waves ready

    // chunk 0: k = 0..255, steps g = 0..7 — no barriers
#pragma unroll
    for (int g = 0; g < 8; ++g) BODY(g, g, g % 3);

    // chunk boundary: all waves done reading B0 -> restage -> visible
    __syncthreads();
    STAGE_B(1);
    __syncthreads();   // drains vmcnt: B1 (and in-flight A) landed

    // chunk 1: k = 256..511, steps g = 8..15 — no barriers
#pragma unroll
    for (int g = 8; g < 16; ++g) BODY(g, g - 8, g % 3);

    // ---- epilogue: s = sigmoid(z+bz)*tanh(h+bh), direct stores ----
    float* fwd = out;
    float* seq = out + (size_t)M_ROWS * 1024;
#pragma unroll
    for (int p = 0; p < 2; ++p) {
        int u = u0 + p * 16 + fr;
        float bz = b_z[u];
        float bh = b_h[u];
#pragma unroll
        for (int m = 0; m < 2; ++m) {
            int rowbase = brow + wid * 32 + m * 16 + ks * 4;
            f32x4 az = acc[m][p];       // z-gate (jj < 32)
            f32x4 ah = acc[m][p + 2];   // h-candidate (jj >= 32), same u
#pragma unroll
            for (int j = 0; j < 4; ++j) {
                float zt = 1.f / (1.f + __expf(-(az[j] + bz)));
                float e  = __expf(2.f * (ah[j] + bh));
                float s  = zt * (1.f - 2.f / (e + 1.f));
                size_t rr = (size_t)(rowbase + j);
                fwd[rr * 1024 + u] = s;
                seq[rr * 512 + u]  = s;
            }
        }
    }
    // zero-fill fwd[:, 512+u0 .. 512+u0+32) for this block's u-range
    const f32x4 z4 = (f32x4){0.f, 0.f, 0.f, 0.f};
#pragma unroll
    for (int i = 0; i < 4; ++i) {
        int id  = i * 256 + tid;        // [0,1024)
        int row = id >> 3;
        int cc  = (id & 7) * 4;
        *reinterpret_cast<f32x4*>(&fwd[(size_t)(brow + row) * 1024 + 512 + u0 + cc]) = z4;
    }
#undef ISSUE_A
#undef STAGE_B
#undef BODY
}

// ---------------------------------------------------------------------------
// Legacy fallback (round-1 kernel, needs no workspace) if ws is too small
// ---------------------------------------------------------------------------
#define LDSS 40
__global__ __launch_bounds__(256) void gru_fused_legacy(
    const float* __restrict__ inp, const float* __restrict__ w_z,
    const float* __restrict__ b_z, const float* __restrict__ w_h,
    const float* __restrict__ b_h, float* __restrict__ out)
{
    __shared__ __align__(16) unsigned short Asl[2][128][LDSS];
    __shared__ __align__(16) unsigned short Bsl[2][128][LDSS];
    const int tid = threadIdx.x, lane = tid & 63, wid = tid >> 6;
    const int wm = wid >> 1, wn = wid & 1;
    const int u0 = blockIdx.x * 64, brow = blockIdx.y * 128;
    f32x4 acc[4][4];
#pragma unroll
    for (int m = 0; m < 4; ++m)
#pragma unroll
        for (int n = 0; n < 4; ++n) acc[m][n] = (f32x4){0.f,0.f,0.f,0.f};
    f32x4 rA[4], rB[4];
#define STAGE_LOAD(kt) { const int k0_=(kt)*32; \
    _Pragma("unroll") for (int it=0; it<4; ++it){ int idx=tid+256*it; int r=idx>>3,c=(idx&7)<<2; \
        rA[it]=*reinterpret_cast<const f32x4*>(inp+(size_t)(brow+r)*IN_STRIDE+k0_+c);} \
    _Pragma("unroll") for (int it=0; it<4; ++it){ int idx=tid+256*it; int jj=idx&127; int k4=(idx>>7)<<2; \
        const float* w_=((jj>>5)&1)?w_h:w_z; int u_=u0+((jj>>6)<<5)+(jj&31); \
        const float* p_=w_+(size_t)(k0_+k4)*UDIM+u_; \
        rB[it][0]=p_[0]; rB[it][1]=p_[UDIM]; rB[it][2]=p_[2*UDIM]; rB[it][3]=p_[3*UDIM];} }
#define STAGE_WRITE(bufi) { \
    _Pragma("unroll") for (int it=0; it<4; ++it){ int idx=tid+256*it; int r=idx>>3,c=(idx&7)<<2; ushort4v v; \
        v[0]=f2bf(rA[it][0]); v[1]=f2bf(rA[it][1]); v[2]=f2bf(rA[it][2]); v[3]=f2bf(rA[it][3]); \
        *reinterpret_cast<ushort4v*>(&Asl[bufi][r][c])=v;} \
    _Pragma("unroll") for (int it=0; it<4; ++it){ int idx=tid+256*it; int jj=idx&127; int k4=(idx>>7)<<2; ushort4v v; \
        v[0]=f2bf(rB[it][0]); v[1]=f2bf(rB[it][1]); v[2]=f2bf(rB[it][2]); v[3]=f2bf(rB[it][3]); \
        *reinterpret_cast<ushort4v*>(&Bsl[bufi][jj][k4])=v;} }
    STAGE_LOAD(0); STAGE_WRITE(0);
    const int fr = lane & 15, koff = (lane >> 4) << 3;
    for (int kt = 0; kt < 16; ++kt) {
        if (kt + 1 < 16) STAGE_LOAD(kt + 1);
        __syncthreads();
        const int buf = kt & 1;
        short8 af[4], bfr[4];
#pragma unroll
        for (int m = 0; m < 4; ++m) af[m] = *reinterpret_cast<const short8*>(&Asl[buf][wm*64+m*16+fr][koff]);
#pragma unroll
        for (int n = 0; n < 4; ++n) bfr[n] = *reinterpret_cast<const short8*>(&Bsl[buf][wn*64+n*16+fr][koff]);
#pragma unroll
        for (int m = 0; m < 4; ++m)
#pragma unroll
            for (int n = 0; n < 4; ++n)
                acc[m][n] = __builtin_amdgcn_mfma_f32_16x16x32_bf16(af[m], bfr[n], acc[m][n], 0, 0, 0);
        if (kt + 1 < 16) STAGE_WRITE((kt + 1) & 1);
    }
    float* fwd = out; float* seq = out + (size_t)M_ROWS * 1024;
    const int fq = lane >> 4;
#pragma unroll
    for (int p = 0; p < 2; ++p) {
        int u = u0 + wn * 32 + p * 16 + fr;
        float bz = b_z[u], bh = b_h[u];
#pragma unroll
        for (int m = 0; m < 4; ++m) {
            int row0 = brow + wm * 64 + m * 16 + fq * 4;
            f32x4 az = acc[m][p], ah = acc[m][p + 2];
#pragma unroll
            for (int j = 0; j < 4; ++j) {
                float zt = 1.f / (1.f + __expf(-(az[j] + bz)));
                float e  = __expf(2.f * (ah[j] + bh));
                float s  = zt * (1.f - 2.f / (e + 1.f));
                size_t rr = (size_t)(row0 + j);
                fwd[rr * 1024 + u] = s;
                fwd[rr * 1024 + 512 + u] = 0.f;
                seq[rr * 512 + u] = s;
            }
        }
    }
}

extern "C" void kernel_launch(void* const* d_in, const int* in_sizes, int n_in,
                              void* d_out, int out_size, void* d_ws, size_t ws_size,
                              hipStream_t stream) {
    const float* inp = (const float*)d_in[0];
    const float* w_z = (const float*)d_in[2];
    const float* b_z = (const float*)d_in[4];
    const float* w_h = (const float*)d_in[8];
    const float* b_h = (const float*)d_in[10];
    float* out = (float*)d_out;

    const size_t needW = (size_t)16 * 2 * 2048 * 16;   // 1 MiB packed weights
    if (ws_size >= needW) {
        unsigned short* Wp = (unsigned short*)d_ws;
        hipLaunchKernelGGL(pack_w, dim3(256), dim3(256), 0, stream, w_z, w_h, Wp);
        hipLaunchKernelGGL(gru_gemm, dim3(2048), dim3(256), 0, stream,
                           inp, Wp, b_z, b_h, out);
    } else {
        hipLaunchKernelGGL(gru_fused_legacy, dim3(8, 128), dim3(256), 0, stream,
                           inp, w_z, b_z, w_h, b_h, out);
    }
}

// Round 17
// 70.612 us; speedup vs baseline: 1.1209x; 1.1209x over previous
//
#include <hip/hip_runtime.h>
#include <hip/hip_bf16.h>

typedef __attribute__((ext_vector_type(4))) float f32x4;
typedef __attribute__((ext_vector_type(8))) short short8;
typedef __attribute__((ext_vector_type(8))) unsigned short ushort8;
typedef __attribute__((ext_vector_type(4))) unsigned short ushort4v;

#define M_ROWS 16384
#define KDIM 512
#define UDIM 512
#define IN_STRIDE 1024
#define NSTEP 16          // K / 32

__device__ __forceinline__ unsigned short f2bf(float f) {
    union { float f; unsigned u; } v; v.f = f;
    unsigned r = v.u + 0x7FFFu + ((v.u >> 16) & 1u);  // RTNE
    return (unsigned short)(r >> 16);
}

// packed RNE f32x2 -> bf16x2 (compiler emits v_cvt_pk_bf16_f32)
__device__ __forceinline__ unsigned cvt2(float a, float b) {
    __hip_bfloat162 h = __float22bfloat162_rn(float2{a, b});
    union { __hip_bfloat162 h; unsigned u; } c; c.h = h; return c.u;
}

// global_load_lds, width 16 (literal required)
#define GLD16(g, l)                                                            \
    __builtin_amdgcn_global_load_lds(                                          \
        (const __attribute__((address_space(1))) void*)(g),                    \
        (__attribute__((address_space(3))) void*)(l), 16, 0, 0)

// ---------------------------------------------------------------------------
// weights pack: Wp[ub 8][kt 16][s 512] x 16B slots, XOR-swizzle baked into
// the k-slot order so gru_gemm's global_load_lds consumes it linearly.
// ---------------------------------------------------------------------------
__global__ __launch_bounds__(256) void pack_w(
    const float* __restrict__ w_z,
    const float* __restrict__ w_h,
    unsigned short* __restrict__ Wp)
{
    int tid = blockIdx.x * 256 + threadIdx.x;   // [0, 65536)
    int s   = tid & 511;
    int kt  = (tid >> 9) & 15;
    int ub  = tid >> 13;
    int jj  = s >> 2;
    int sl  = (s & 3) ^ ((jj >> 1) & 3);
    int k   = kt * 32 + sl * 8;
    const float* w = ((jj >> 5) & 1) ? w_h : w_z;
    int u = ub * 64 + ((jj >> 6) << 5) + (jj & 31);
    ushort8 v;
#pragma unroll
    for (int i = 0; i < 8; ++i)
        v[i] = f2bf(w[(size_t)(k + i) * UDIM + u]);
    *reinterpret_cast<ushort8*>(Wp + (size_t)tid * 8) = v;
}

// ---------------------------------------------------------------------------
// Fused GEMM (R9/R15 structure, cvt+ds_write moved OFF the barrier tail):
// 128x128 tile, BK=32, 4 waves.
//  A: x fp32 -> depth-3 register ring (A(t+1) lands a full step early) ->
//     v_cvt_pk_bf16_f32 + ds_write_b128 placed BEFORE the MFMA block
//     (overlaps MFMA issue; not in the vmcnt->barrier chain). 2 LDS bufs.
//  B: packed Wp via global_load_lds, ring-2, issued FIRST each step.
//  End-of-step: vmcnt(4) (only A(t+3) in flight) -> lgkmcnt(0) -> s_barrier.
// ---------------------------------------------------------------------------
__global__ __launch_bounds__(256, 4) void gru_gemm(
    const float* __restrict__ x,            // (16384, 1024), cols [0,512) used
    const unsigned short* __restrict__ Wp,  // packed weights
    const float* __restrict__ b_z,
    const float* __restrict__ b_h,
    float* __restrict__ out)
{
    __shared__ __align__(16) unsigned char smem[33792];
    unsigned short* shA = (unsigned short*)smem;            // 2 bufs x 4096 u16
    unsigned short* shB = (unsigned short*)(smem + 16384);  // 2 bufs x 4096 u16

    const int tid  = threadIdx.x;
    const int lane = tid & 63;
    const int wid  = tid >> 6;
    const int wm   = wid >> 1;
    const int wn   = wid & 1;

    // XCD-aware swizzle: the 8 u-blocks of a row-panel land on one XCD
    const int d  = blockIdx.x;               // [0,1024)
    const int bx = (d >> 3) & 7;             // u-block
    const int by = (d & 7) * 16 + (d >> 6);  // row-panel
    const int u0   = bx * 64;
    const int brow = by * 128;

    // ---- A staging: thread owns 2 16B LDS slots; slot s -> row r=s>>2,
    //      piece p=s&3; content = global k-octet q = p ^ ((r>>1)&3) ----
    const int s0a = wid * 128 + lane;
    const int s1a = s0a + 64;
    const int r0 = s0a >> 2, r1 = s1a >> 2;
    const int q0 = (s0a & 3) ^ ((r0 >> 1) & 3);
    const int q1 = (s1a & 3) ^ ((r1 >> 1) & 3);
    const float* gA0 = x + (size_t)(brow + r0) * IN_STRIDE + q0 * 8;
    const float* gA1 = x + (size_t)(brow + r1) * IN_STRIDE + q1 * 8;

    const unsigned short* bp = Wp + (size_t)bx * 65536 + (size_t)s0a * 8;

    f32x4 acc[4][4];
#pragma unroll
    for (int m = 0; m < 4; ++m)
#pragma unroll
        for (int n = 0; n < 4; ++n)
            acc[m][n] = (f32x4){0.f, 0.f, 0.f, 0.f};

    f32x4 rA[3][4];   // depth-3 A ring; all indices static under full unroll

#define ISSUE_AREG(t, set)                                                     \
    {                                                                          \
        rA[set][0] = *reinterpret_cast<const f32x4*>(gA0 + (t) * 32);          \
        rA[set][1] = *reinterpret_cast<const f32x4*>(gA0 + (t) * 32 + 4);      \
        rA[set][2] = *reinterpret_cast<const f32x4*>(gA1 + (t) * 32);          \
        rA[set][3] = *reinterpret_cast<const f32x4*>(gA1 + (t) * 32 + 4);      \
    }

#define ISSUE_B(t, b)                                                          \
    {                                                                          \
        GLD16(bp + (size_t)(t) * 4096,       shB + (b) * 4096 + wid * 1024);   \
        GLD16(bp + (size_t)(t) * 4096 + 512, shB + (b) * 4096 + wid * 1024 + 512); \
    }

#define CVT_WRITE_A(set, b)                                                    \
    {                                                                          \
        union { unsigned u[4]; ushort8 v; } c0, c1;                            \
        c0.u[0] = cvt2(rA[set][0][0], rA[set][0][1]);                          \
        c0.u[1] = cvt2(rA[set][0][2], rA[set][0][3]);                          \
        c0.u[2] = cvt2(rA[set][1][0], rA[set][1][1]);                          \
        c0.u[3] = cvt2(rA[set][1][2], rA[set][1][3]);                          \
        c1.u[0] = cvt2(rA[set][2][0], rA[set][2][1]);                          \
        c1.u[1] = cvt2(rA[set][2][2], rA[set][2][3]);                          \
        c1.u[2] = cvt2(rA[set][3][0], rA[set][3][1]);                          \
        c1.u[3] = cvt2(rA[set][3][2], rA[set][3][3]);                          \
        *reinterpret_cast<ushort8*>(&shA[(b) * 4096 + s0a * 8]) = c0.v;        \
        *reinterpret_cast<ushort8*>(&shA[(b) * 4096 + s1a * 8]) = c1.v;        \
    }

    // fragment read offsets (ushort units), xo swizzle (R4-proven, both tiles)
    const int fr = lane & 15;
    const int ks = lane >> 4;
    const int xo = (fr >> 1) & 3;
    int aoff[4], boff[4];
#pragma unroll
    for (int m = 0; m < 4; ++m)
        aoff[m] = (wm * 64 + m * 16 + fr) * 32 + ((ks ^ xo) << 3);
#pragma unroll
    for (int n = 0; n < 4; ++n)
        boff[n] = (wn * 64 + n * 16 + fr) * 32 + ((ks ^ xo) << 3);

    // prologue: A0,B0,A1,A2 in flight; land A0+B0+A1 (leave A2); write A(0)
    ISSUE_AREG(0, 0);
    ISSUE_B(0, 0);
    ISSUE_AREG(1, 1);
    ISSUE_AREG(2, 2);
    asm volatile("s_waitcnt vmcnt(4)" ::: "memory");   // A2 (newest 4) in flight
    CVT_WRITE_A(0, 0);
    asm volatile("s_waitcnt lgkmcnt(0)" ::: "memory");
    asm volatile("s_barrier" ::: "memory");

#pragma unroll
    for (int t = 0; t < NSTEP; ++t) {
        // 1. B(t+1) first: gets frag-read + cvt + MFMA time to land
        if (t + 1 < NSTEP) ISSUE_B(t + 1, (t + 1) & 1);
        // 2. fragment reads of step t
        const int ba = t & 1, bb = t & 1;
        short8 af[4], bfrag[4];
#pragma unroll
        for (int m = 0; m < 4; ++m)
            af[m] = *reinterpret_cast<const short8*>(&shA[ba * 4096 + aoff[m]]);
#pragma unroll
        for (int n = 0; n < 4; ++n)
            bfrag[n] = *reinterpret_cast<const short8*>(&shB[bb * 4096 + boff[n]]);
        // 3. cvt+write A(t+1) NOW (regs landed at end of t-1; target buf
        //    (t+1)&1 was last read at t-1, behind a fenced barrier)
        if (t + 1 < NSTEP) CVT_WRITE_A((t + 1) % 3 == 0 ? 0 : ((t + 1) % 3), (t + 1) & 1);
        // 4. issue A(t+3) into the set freed by step t-1's cvt
        if (t + 3 < NSTEP) ISSUE_AREG(t + 3, (t + 3) % 3);
        // 5. MFMA block (overlaps the cvt VALU + in-flight loads)
#pragma unroll
        for (int m = 0; m < 4; ++m)
#pragma unroll
            for (int n = 0; n < 4; ++n)
                acc[m][n] = __builtin_amdgcn_mfma_f32_16x16x32_bf16(af[m], bfrag[n], acc[m][n], 0, 0, 0);
        // 6. tail: counted vmcnt (A(t+3) stays in flight), drain LDS, barrier
        if (t + 1 < NSTEP) {
            if (t + 3 < NSTEP) {
                asm volatile("s_waitcnt vmcnt(4)" ::: "memory");
            } else {
                asm volatile("s_waitcnt vmcnt(0)" ::: "memory");
            }
            asm volatile("s_waitcnt lgkmcnt(0)" ::: "memory");
            asm volatile("s_barrier" ::: "memory");
        }
    }

    __syncthreads();   // full fence before LDS reuse (drains lgkm+vm per wave)

    // ---- epilogue: s = sigmoid(z+bz)*tanh(h+bh) in regs -> LDS plane ----
    float* plane = (float*)smem;   // [128][66] f32 = 33792 B, fits exactly
    const int fq = lane >> 4;
#pragma unroll
    for (int p = 0; p < 2; ++p) {
        int ucol = wn * 32 + p * 16 + fr;
        float bz = b_z[u0 + ucol];
        float bh = b_h[u0 + ucol];
#pragma unroll
        for (int m = 0; m < 4; ++m) {
            int row0 = wm * 64 + m * 16 + fq * 4;
            f32x4 az = acc[m][p];
            f32x4 ah = acc[m][p + 2];
#pragma unroll
            for (int j = 0; j < 4; ++j) {
                float zt = 1.f / (1.f + __expf(-(az[j] + bz)));
                float e  = __expf(2.f * (ah[j] + bh));
                float s  = zt * (1.f - 2.f / (e + 1.f));
                plane[(row0 + j) * 66 + ucol] = s;
            }
        }
    }
    __syncthreads();

    // ---- transposed float4 stores: 256B contiguous per quarter-wave ----
    float* fwd = out;
    float* seq = out + (size_t)M_ROWS * 1024;
    const f32x4 z4 = (f32x4){0.f, 0.f, 0.f, 0.f};
    const int c4 = (tid & 15) * 4;
#pragma unroll
    for (int it = 0; it < 8; ++it) {
        int row = it * 16 + (tid >> 4);
        f32x4 v = *reinterpret_cast<const f32x4*>(&plane[row * 66 + c4]);
        size_t grow = (size_t)(brow + row);
        *reinterpret_cast<f32x4*>(&fwd[grow * 1024 + u0 + c4])       = v;
        *reinterpret_cast<f32x4*>(&fwd[grow * 1024 + 512 + u0 + c4]) = z4;
        *reinterpret_cast<f32x4*>(&seq[grow * 512 + u0 + c4])        = v;
    }
#undef ISSUE_AREG
#undef ISSUE_B
#undef CVT_WRITE_A
}

// ---------------------------------------------------------------------------
// Legacy fallback (round-1 kernel, needs no workspace) if ws is too small
// ---------------------------------------------------------------------------
#define LDSS 40
__global__ __launch_bounds__(256) void gru_fused_legacy(
    const float* __restrict__ inp, const float* __restrict__ w_z,
    const float* __restrict__ b_z, const float* __restrict__ w_h,
    const float* __restrict__ b_h, float* __restrict__ out)
{
    __shared__ __align__(16) unsigned short Asl[2][128][LDSS];
    __shared__ __align__(16) unsigned short Bsl[2][128][LDSS];
    const int tid = threadIdx.x, lane = tid & 63, wid = tid >> 6;
    const int wm = wid >> 1, wn = wid & 1;
    const int u0 = blockIdx.x * 64, brow = blockIdx.y * 128;
    f32x4 acc[4][4];
#pragma unroll
    for (int m = 0; m < 4; ++m)
#pragma unroll
        for (int n = 0; n < 4; ++n) acc[m][n] = (f32x4){0.f,0.f,0.f,0.f};
    f32x4 rA[4], rB[4];
#define STAGE_LOAD(kt) { const int k0_=(kt)*32; \
    _Pragma("unroll") for (int it=0; it<4; ++it){ int idx=tid+256*it; int r=idx>>3,c=(idx&7)<<2; \
        rA[it]=*reinterpret_cast<const f32x4*>(inp+(size_t)(brow+r)*IN_STRIDE+k0_+c);} \
    _Pragma("unroll") for (int it=0; it<4; ++it){ int idx=tid+256*it; int jj=idx&127; int k4=(idx>>7)<<2; \
        const float* w_=((jj>>5)&1)?w_h:w_z; int u_=u0+((jj>>6)<<5)+(jj&31); \
        const float* p_=w_+(size_t)(k0_+k4)*UDIM+u_; \
        rB[it][0]=p_[0]; rB[it][1]=p_[UDIM]; rB[it][2]=p_[2*UDIM]; rB[it][3]=p_[3*UDIM];} }
#define STAGE_WRITE(bufi) { \
    _Pragma("unroll") for (int it=0; it<4; ++it){ int idx=tid+256*it; int r=idx>>3,c=(idx&7)<<2; ushort4v v; \
        v[0]=f2bf(rA[it][0]); v[1]=f2bf(rA[it][1]); v[2]=f2bf(rA[it][2]); v[3]=f2bf(rA[it][3]); \
        *reinterpret_cast<ushort4v*>(&Asl[bufi][r][c])=v;} \
    _Pragma("unroll") for (int it=0; it<4; ++it){ int idx=tid+256*it; int jj=idx&127; int k4=(idx>>7)<<2; ushort4v v; \
        v[0]=f2bf(rB[it][0]); v[1]=f2bf(rB[it][1]); v[2]=f2bf(rB[it][2]); v[3]=f2bf(rB[it][3]); \
        *reinterpret_cast<ushort4v*>(&Bsl[bufi][jj][k4])=v;} }
    STAGE_LOAD(0); STAGE_WRITE(0);
    const int fr = lane & 15, koff = (lane >> 4) << 3;
    for (int kt = 0; kt < 16; ++kt) {
        if (kt + 1 < 16) STAGE_LOAD(kt + 1);
        __syncthreads();
        const int buf = kt & 1;
        short8 af[4], bfr[4];
#pragma unroll
        for (int m = 0; m < 4; ++m) af[m] = *reinterpret_cast<const short8*>(&Asl[buf][wm*64+m*16+fr][koff]);
#pragma unroll
        for (int n = 0; n < 4; ++n) bfr[n] = *reinterpret_cast<const short8*>(&Bsl[buf][wn*64+n*16+fr][koff]);
#pragma unroll
        for (int m = 0; m < 4; ++m)
#pragma unroll
            for (int n = 0; n < 4; ++n)
                acc[m][n] = __builtin_amdgcn_mfma_f32_16x16x32_bf16(af[m], bfr[n], acc[m][n], 0, 0, 0);
        if (kt + 1 < 16) STAGE_WRITE((kt + 1) & 1);
    }
    float* fwd = out; float* seq = out + (size_t)M_ROWS * 1024;
    const int fq = lane >> 4;
#pragma unroll
    for (int p = 0; p < 2; ++p) {
        int u = u0 + wn * 32 + p * 16 + fr;
        float bz = b_z[u], bh = b_h[u];
#pragma unroll
        for (int m = 0; m < 4; ++m) {
            int row0 = brow + wm * 64 + m * 16 + fq * 4;
            f32x4 az = acc[m][p], ah = acc[m][p + 2];
#pragma unroll
            for (int j = 0; j < 4; ++j) {
                float zt = 1.f / (1.f + __expf(-(az[j] + bz)));
                float e  = __expf(2.f * (ah[j] + bh));
                float s  = zt * (1.f - 2.f / (e + 1.f));
                size_t rr = (size_t)(row0 + j);
                fwd[rr * 1024 + u] = s;
                fwd[rr * 1024 + 512 + u] = 0.f;
                seq[rr * 512 + u] = s;
            }
        }
    }
}

extern "C" void kernel_launch(void* const* d_in, const int* in_sizes, int n_in,
                              void* d_out, int out_size, void* d_ws, size_t ws_size,
                              hipStream_t stream) {
    const float* inp = (const float*)d_in[0];
    const float* w_z = (const float*)d_in[2];
    const float* b_z = (const float*)d_in[4];
    const float* w_h = (const float*)d_in[8];
    const float* b_h = (const float*)d_in[10];
    float* out = (float*)d_out;

    const size_t needW = (size_t)8 * 16 * 512 * 16;   // 1 MiB packed weights
    if (ws_size >= needW) {
        unsigned short* Wp = (unsigned short*)d_ws;
        hipLaunchKernelGGL(pack_w, dim3(256), dim3(256), 0, stream, w_z, w_h, Wp);
        hipLaunchKernelGGL(gru_gemm, dim3(1024), dim3(256), 0, stream,
                           inp, Wp, b_z, b_h, out);
    } else {
        hipLaunchKernelGGL(gru_fused_legacy, dim3(8, 128), dim3(256), 0, stream,
                           inp, w_z, b_z, w_h, b_h, out);
    }
}

// Round 18
// 49.757 us; speedup vs baseline: 1.5907x; 1.4191x over previous
//
#include <hip/hip_runtime.h>
#include <hip/hip_bf16.h>

typedef __attribute__((ext_vector_type(4))) float f32x4;
typedef __attribute__((ext_vector_type(8))) short short8;
typedef __attribute__((ext_vector_type(8))) unsigned short ushort8;
typedef __attribute__((ext_vector_type(4))) unsigned short ushort4v;

#define M_ROWS 16384
#define KDIM 512
#define UDIM 512
#define IN_STRIDE 1024
#define NSTEP 16          // K / 32

__device__ __forceinline__ unsigned short f2bf(float f) {
    union { float f; unsigned u; } v; v.f = f;
    unsigned r = v.u + 0x7FFFu + ((v.u >> 16) & 1u);  // RTNE
    return (unsigned short)(r >> 16);
}

// packed RNE f32x2 -> bf16x2 (compiler emits v_cvt_pk_bf16_f32)
__device__ __forceinline__ unsigned cvt2(float a, float b) {
    __hip_bfloat162 h = __float22bfloat162_rn(float2{a, b});
    union { __hip_bfloat162 h; unsigned u; } c; c.h = h; return c.u;
}

// global_load_lds, width 16 (literal required)
#define GLD16(g, l)                                                            \
    __builtin_amdgcn_global_load_lds(                                          \
        (const __attribute__((address_space(1))) void*)(g),                    \
        (__attribute__((address_space(3))) void*)(l), 16, 0, 0)

// ---------------------------------------------------------------------------
// weights pack: Wp[ub 8][kt 16][s 512] x 16B slots, XOR-swizzle baked into
// the k-slot order so gru_gemm's global_load_lds consumes it linearly.
// ---------------------------------------------------------------------------
__global__ __launch_bounds__(256) void pack_w(
    const float* __restrict__ w_z,
    const float* __restrict__ w_h,
    unsigned short* __restrict__ Wp)
{
    int tid = blockIdx.x * 256 + threadIdx.x;   // [0, 65536)
    int s   = tid & 511;
    int kt  = (tid >> 9) & 15;
    int ub  = tid >> 13;
    int jj  = s >> 2;
    int sl  = (s & 3) ^ ((jj >> 1) & 3);
    int k   = kt * 32 + sl * 8;
    const float* w = ((jj >> 5) & 1) ? w_h : w_z;
    int u = ub * 64 + ((jj >> 6) << 5) + (jj & 31);
    ushort8 v;
#pragma unroll
    for (int i = 0; i < 8; ++i)
        v[i] = f2bf(w[(size_t)(k + i) * UDIM + u]);
    *reinterpret_cast<ushort8*>(Wp + (size_t)tid * 8) = v;
}

// ---------------------------------------------------------------------------
// Fused GEMM (R14 structure + depth-3 A ring, spill-proof):
// 128x128 tile, BK=32, 4 waves, LDS 40960 B (A: 2x8KB, B: 3x8KB).
//  A: x fp32 -> NAMED register sets a0/a1/a2 (16 f32 each; zero runtime
//     indexing -> cannot spill) issued 3 steps ahead (~2 steps of slack
//     over HBM/L3 latency); v_cvt_pk_bf16_f32 + swizzled ds_write placed
//     BEFORE the MFMA block (off the barrier tail).
//  B: packed Wp via global_load_lds, ring-3, 2-step lookahead.
//  Tail: vmcnt(6) = A(t+3)x4 + B(t+2)x2 in flight -> lgkmcnt(0) -> barrier.
//  16 K-steps written as explicit macro calls with literal set indices.
// ---------------------------------------------------------------------------
__global__ __launch_bounds__(256, 3) void gru_gemm(
    const float* __restrict__ x,            // (16384, 1024), cols [0,512) used
    const unsigned short* __restrict__ Wp,  // packed weights
    const float* __restrict__ b_z,
    const float* __restrict__ b_h,
    float* __restrict__ out)
{
    __shared__ __align__(16) unsigned char smem[40960];
    unsigned short* shA = (unsigned short*)smem;            // 2 bufs x 4096 u16
    unsigned short* shB = (unsigned short*)(smem + 16384);  // 3 bufs x 4096 u16

    const int tid  = threadIdx.x;
    const int lane = tid & 63;
    const int wid  = tid >> 6;
    const int wm   = wid >> 1;
    const int wn   = wid & 1;

    // XCD-aware swizzle: the 8 u-blocks of a row-panel land on one XCD
    const int d  = blockIdx.x;               // [0,1024)
    const int bx = (d >> 3) & 7;             // u-block
    const int by = (d & 7) * 16 + (d >> 6);  // row-panel
    const int u0   = bx * 64;
    const int brow = by * 128;

    // ---- A staging: thread owns 2 16B LDS slots; slot s -> row r=s>>2,
    //      piece p=s&3; content = global k-octet q = p ^ ((r>>1)&3) ----
    const int s0a = wid * 128 + lane;
    const int s1a = s0a + 64;
    const int r0 = s0a >> 2, r1 = s1a >> 2;
    const int q0 = (s0a & 3) ^ ((r0 >> 1) & 3);
    const int q1 = (s1a & 3) ^ ((r1 >> 1) & 3);
    const float* gA0 = x + (size_t)(brow + r0) * IN_STRIDE + q0 * 8;
    const float* gA1 = x + (size_t)(brow + r1) * IN_STRIDE + q1 * 8;

    const unsigned short* bp = Wp + (size_t)bx * 65536 + (size_t)s0a * 8;

    f32x4 acc[4][4];
#pragma unroll
    for (int m = 0; m < 4; ++m)
#pragma unroll
        for (int n = 0; n < 4; ++n)
            acc[m][n] = (f32x4){0.f, 0.f, 0.f, 0.f};

    // A ring: three NAMED sets, never runtime-indexed (spill-proof)
    f32x4 a0_0, a0_1, a0_2, a0_3;
    f32x4 a1_0, a1_1, a1_2, a1_3;
    f32x4 a2_0, a2_1, a2_2, a2_3;

#define ISSUE_A_(t, s)                                                         \
    {                                                                          \
        a##s##_0 = *reinterpret_cast<const f32x4*>(gA0 + (t) * 32);            \
        a##s##_1 = *reinterpret_cast<const f32x4*>(gA0 + (t) * 32 + 4);        \
        a##s##_2 = *reinterpret_cast<const f32x4*>(gA1 + (t) * 32);            \
        a##s##_3 = *reinterpret_cast<const f32x4*>(gA1 + (t) * 32 + 4);        \
    }
#define ISSUE_A(t, s) ISSUE_A_(t, s)

#define ISSUE_B(t, b)                                                          \
    {                                                                          \
        GLD16(bp + (size_t)(t) * 4096,       shB + (b) * 4096 + wid * 1024);   \
        GLD16(bp + (size_t)(t) * 4096 + 512, shB + (b) * 4096 + wid * 1024 + 512); \
    }

#define CVT_WRITE_A_(s, b)                                                     \
    {                                                                          \
        union { unsigned u[4]; ushort8 v; } c0, c1;                            \
        c0.u[0] = cvt2(a##s##_0[0], a##s##_0[1]);                              \
        c0.u[1] = cvt2(a##s##_0[2], a##s##_0[3]);                              \
        c0.u[2] = cvt2(a##s##_1[0], a##s##_1[1]);                              \
        c0.u[3] = cvt2(a##s##_1[2], a##s##_1[3]);                              \
        c1.u[0] = cvt2(a##s##_2[0], a##s##_2[1]);                              \
        c1.u[1] = cvt2(a##s##_2[2], a##s##_2[3]);                              \
        c1.u[2] = cvt2(a##s##_3[0], a##s##_3[1]);                              \
        c1.u[3] = cvt2(a##s##_3[2], a##s##_3[3]);                              \
        *reinterpret_cast<ushort8*>(&shA[(b) * 4096 + s0a * 8]) = c0.v;        \
        *reinterpret_cast<ushort8*>(&shA[(b) * 4096 + s1a * 8]) = c1.v;        \
    }
#define CVT_WRITE_A(s, b) CVT_WRITE_A_(s, b)

#define VMWAIT_(n) asm volatile("s_waitcnt vmcnt(" #n ")" ::: "memory")
#define VMWAIT(n) VMWAIT_(n)

    // fragment read offsets (ushort units), xo swizzle (R4-proven, both tiles)
    const int fr = lane & 15;
    const int ks = lane >> 4;
    const int xo = (fr >> 1) & 3;
    int aoff[4], boff[4];
#pragma unroll
    for (int m = 0; m < 4; ++m)
        aoff[m] = (wm * 64 + m * 16 + fr) * 32 + ((ks ^ xo) << 3);
#pragma unroll
    for (int n = 0; n < 4; ++n)
        boff[n] = (wn * 64 + n * 16 + fr) * 32 + ((ks ^ xo) << 3);

    // prologue: A0,B0,A1,B1,A2 issued; land A(0)+B(0) (10 newest in flight)
    ISSUE_A(0, 0);
    ISSUE_B(0, 0);
    ISSUE_A(1, 1);
    ISSUE_B(1, 1);
    ISSUE_A(2, 2);
    VMWAIT(10);
    CVT_WRITE_A(0, 0);
    asm volatile("s_waitcnt lgkmcnt(0)" ::: "memory");
    asm volatile("s_barrier" ::: "memory");

    // step T: read bufA T&1 / bufB T%3; CVT set SW=(T+1)%3 -> bufA (T+1)&1;
    // issue B(T+2)->buf (T+2)%3 and A(T+3)->set SI=T%3; tail vmcnt(VM).
#define STEP(T, SW, SI, VM)                                                    \
    {                                                                          \
        if ((T) + 2 < NSTEP) ISSUE_B((T) + 2, ((T) + 2) % 3);                  \
        short8 af[4], bfrag[4];                                                \
        _Pragma("unroll")                                                      \
        for (int m = 0; m < 4; ++m)                                            \
            af[m] = *reinterpret_cast<const short8*>(                          \
                &shA[((T) & 1) * 4096 + aoff[m]]);                             \
        _Pragma("unroll")                                                      \
        for (int n = 0; n < 4; ++n)                                            \
            bfrag[n] = *reinterpret_cast<const short8*>(                       \
                &shB[((T) % 3) * 4096 + boff[n]]);                             \
        if ((T) + 1 < NSTEP) CVT_WRITE_A(SW, ((T) + 1) & 1);                   \
        if ((T) + 3 < NSTEP) ISSUE_A((T) + 3, SI);                             \
        _Pragma("unroll")                                                      \
        for (int m = 0; m < 4; ++m)                                            \
            _Pragma("unroll")                                                  \
            for (int n = 0; n < 4; ++n)                                        \
                acc[m][n] = __builtin_amdgcn_mfma_f32_16x16x32_bf16(           \
                    af[m], bfrag[n], acc[m][n], 0, 0, 0);                      \
        if ((T) + 1 < NSTEP) {                                                 \
            VMWAIT(VM);                                                        \
            asm volatile("s_waitcnt lgkmcnt(0)" ::: "memory");                 \
            asm volatile("s_barrier" ::: "memory");                            \
        }                                                                      \
    }

    STEP(0, 1, 0, 6)   STEP(1, 2, 1, 6)   STEP(2, 0, 2, 6)   STEP(3, 1, 0, 6)
    STEP(4, 2, 1, 6)   STEP(5, 0, 2, 6)   STEP(6, 1, 0, 6)   STEP(7, 2, 1, 6)
    STEP(8, 0, 2, 6)   STEP(9, 1, 0, 6)   STEP(10, 2, 1, 6)  STEP(11, 0, 2, 6)
    STEP(12, 1, 0, 6)  STEP(13, 2, 1, 2)  STEP(14, 0, 2, 0)  STEP(15, 1, 0, 0)

    __syncthreads();   // full fence before LDS reuse (drains lgkm+vm per wave)

    // ---- epilogue: s = sigmoid(z+bz)*tanh(h+bh) in regs -> LDS plane ----
    float* plane = (float*)smem;   // [128][68] f32 = 34816 B, fits in 40960
    const int fq = lane >> 4;
#pragma unroll
    for (int p = 0; p < 2; ++p) {
        int ucol = wn * 32 + p * 16 + fr;
        float bz = b_z[u0 + ucol];
        float bh = b_h[u0 + ucol];
#pragma unroll
        for (int m = 0; m < 4; ++m) {
            int row0 = wm * 64 + m * 16 + fq * 4;
            f32x4 az = acc[m][p];
            f32x4 ah = acc[m][p + 2];
#pragma unroll
            for (int j = 0; j < 4; ++j) {
                float zt = 1.f / (1.f + __expf(-(az[j] + bz)));
                float e  = __expf(2.f * (ah[j] + bh));
                float s  = zt * (1.f - 2.f / (e + 1.f));
                plane[(row0 + j) * 68 + ucol] = s;
            }
        }
    }
    __syncthreads();

    // ---- transposed float4 stores: 256B contiguous per quarter-wave ----
    float* fwd = out;
    float* seq = out + (size_t)M_ROWS * 1024;
    const f32x4 z4 = (f32x4){0.f, 0.f, 0.f, 0.f};
    const int c4 = (tid & 15) * 4;
#pragma unroll
    for (int it = 0; it < 8; ++it) {
        int row = it * 16 + (tid >> 4);
        f32x4 v = *reinterpret_cast<const f32x4*>(&plane[row * 68 + c4]);
        size_t grow = (size_t)(brow + row);
        *reinterpret_cast<f32x4*>(&fwd[grow * 1024 + u0 + c4])       = v;
        *reinterpret_cast<f32x4*>(&fwd[grow * 1024 + 512 + u0 + c4]) = z4;
        *reinterpret_cast<f32x4*>(&seq[grow * 512 + u0 + c4])        = v;
    }
#undef STEP
#undef ISSUE_A
#undef ISSUE_A_
#undef ISSUE_B
#undef CVT_WRITE_A
#undef CVT_WRITE_A_
#undef VMWAIT
#undef VMWAIT_
}

// ---------------------------------------------------------------------------
// Legacy fallback (round-1 kernel, needs no workspace) if ws is too small
// ---------------------------------------------------------------------------
#define LDSS 40
__global__ __launch_bounds__(256) void gru_fused_legacy(
    const float* __restrict__ inp, const float* __restrict__ w_z,
    const float* __restrict__ b_z, const float* __restrict__ w_h,
    const float* __restrict__ b_h, float* __restrict__ out)
{
    __shared__ __align__(16) unsigned short Asl[2][128][LDSS];
    __shared__ __align__(16) unsigned short Bsl[2][128][LDSS];
    const int tid = threadIdx.x, lane = tid & 63, wid = tid >> 6;
    const int wm = wid >> 1, wn = wid & 1;
    const int u0 = blockIdx.x * 64, brow = blockIdx.y * 128;
    f32x4 acc[4][4];
#pragma unroll
    for (int m = 0; m < 4; ++m)
#pragma unroll
        for (int n = 0; n < 4; ++n) acc[m][n] = (f32x4){0.f,0.f,0.f,0.f};
    f32x4 rA[4], rB[4];
#define STAGE_LOAD(kt) { const int k0_=(kt)*32; \
    _Pragma("unroll") for (int it=0; it<4; ++it){ int idx=tid+256*it; int r=idx>>3,c=(idx&7)<<2; \
        rA[it]=*reinterpret_cast<const f32x4*>(inp+(size_t)(brow+r)*IN_STRIDE+k0_+c);} \
    _Pragma("unroll") for (int it=0; it<4; ++it){ int idx=tid+256*it; int jj=idx&127; int k4=(idx>>7)<<2; \
        const float* w_=((jj>>5)&1)?w_h:w_z; int u_=u0+((jj>>6)<<5)+(jj&31); \
        const float* p_=w_+(size_t)(k0_+k4)*UDIM+u_; \
        rB[it][0]=p_[0]; rB[it][1]=p_[UDIM]; rB[it][2]=p_[2*UDIM]; rB[it][3]=p_[3*UDIM];} }
#define STAGE_WRITE(bufi) { \
    _Pragma("unroll") for (int it=0; it<4; ++it){ int idx=tid+256*it; int r=idx>>3,c=(idx&7)<<2; ushort4v v; \
        v[0]=f2bf(rA[it][0]); v[1]=f2bf(rA[it][1]); v[2]=f2bf(rA[it][2]); v[3]=f2bf(rA[it][3]); \
        *reinterpret_cast<ushort4v*>(&Asl[bufi][r][c])=v;} \
    _Pragma("unroll") for (int it=0; it<4; ++it){ int idx=tid+256*it; int jj=idx&127; int k4=(idx>>7)<<2; ushort4v v; \
        v[0]=f2bf(rB[it][0]); v[1]=f2bf(rB[it][1]); v[2]=f2bf(rB[it][2]); v[3]=f2bf(rB[it][3]); \
        *reinterpret_cast<ushort4v*>(&Bsl[bufi][jj][k4])=v;} }
    STAGE_LOAD(0); STAGE_WRITE(0);
    const int fr = lane & 15, koff = (lane >> 4) << 3;
    for (int kt = 0; kt < 16; ++kt) {
        if (kt + 1 < 16) STAGE_LOAD(kt + 1);
        __syncthreads();
        const int buf = kt & 1;
        short8 af[4], bfr[4];
#pragma unroll
        for (int m = 0; m < 4; ++m) af[m] = *reinterpret_cast<const short8*>(&Asl[buf][wm*64+m*16+fr][koff]);
#pragma unroll
        for (int n = 0; n < 4; ++n) bfr[n] = *reinterpret_cast<const short8*>(&Bsl[buf][wn*64+n*16+fr][koff]);
#pragma unroll
        for (int m = 0; m < 4; ++m)
#pragma unroll
            for (int n = 0; n < 4; ++n)
                acc[m][n] = __builtin_amdgcn_mfma_f32_16x16x32_bf16(af[m], bfr[n], acc[m][n], 0, 0, 0);
        if (kt + 1 < 16) STAGE_WRITE((kt + 1) & 1);
    }
    float* fwd = out; float* seq = out + (size_t)M_ROWS * 1024;
    const int fq = lane >> 4;
#pragma unroll
    for (int p = 0; p < 2; ++p) {
        int u = u0 + wn * 32 + p * 16 + fr;
        float bz = b_z[u], bh = b_h[u];
#pragma unroll
        for (int m = 0; m < 4; ++m) {
            int row0 = brow + wm * 64 + m * 16 + fq * 4;
            f32x4 az = acc[m][p], ah = acc[m][p + 2];
#pragma unroll
            for (int j = 0; j < 4; ++j) {
                float zt = 1.f / (1.f + __expf(-(az[j] + bz)));
                float e  = __expf(2.f * (ah[j] + bh));
                float s  = zt * (1.f - 2.f / (e + 1.f));
                size_t rr = (size_t)(row0 + j);
                fwd[rr * 1024 + u] = s;
                fwd[rr * 1024 + 512 + u] = 0.f;
                seq[rr * 512 + u] = s;
            }
        }
    }
}

extern "C" void kernel_launch(void* const* d_in, const int* in_sizes, int n_in,
                              void* d_out, int out_size, void* d_ws, size_t ws_size,
                              hipStream_t stream) {
    const float* inp = (const float*)d_in[0];
    const float* w_z = (const float*)d_in[2];
    const float* b_z = (const float*)d_in[4];
    const float* w_h = (const float*)d_in[8];
    const float* b_h = (const float*)d_in[10];
    float* out = (float*)d_out;

    const size_t needW = (size_t)8 * 16 * 512 * 16;   // 1 MiB packed weights
    if (ws_size >= needW) {
        unsigned short* Wp = (unsigned short*)d_ws;
        hipLaunchKernelGGL(pack_w, dim3(256), dim3(256), 0, stream, w_z, w_h, Wp);
        hipLaunchKernelGGL(gru_gemm, dim3(1024), dim3(256), 0, stream,
                           inp, Wp, b_z, b_h, out);
    } else {
        hipLaunchKernelGGL(gru_fused_legacy, dim3(8, 128), dim3(256), 0, stream,
                           inp, w_z, b_z, w_h, b_h, out);
    }
}